// Round 8
// baseline (94.070 us; speedup 1.0000x reference)
//
#include <hip/hip_runtime.h>

#define KE_KCAL 332.0637f

constexpr int N_ATOMS = 6144;
constexpr int NREAL = 1200;             // sum_{bi<24} (96 - 4*bi)
constexpr int NPRED = 384;              // pred blocks (16 atoms each)
constexpr int PAD = 32;                 // 32 words = 128 B, one L2 line/slot

// ---------------- kernel A: pred + per-block sums + pack + zero scratch -----
__global__ __launch_bounds__(256) void pred_kernel(
    const float* __restrict__ f, const int* __restrict__ z,
    const float* __restrict__ w, const float* __restrict__ ztab,
    const float* __restrict__ xyz,
    float* __restrict__ qpart, float4* __restrict__ xqp,
    float* __restrict__ epart, unsigned int* __restrict__ ctr1,
    unsigned int* __restrict__ ctr2)
{
    int t = threadIdx.x, b = blockIdx.x;
    int lane = t & 63, wid = t >> 6;

    if (b == 0) {
        if (t < 64) { epart[t * PAD] = 0.f; ctr1[t * PAD] = 0u; }
        if (t == 64) *ctr2 = 0u;
    }

    int base = b * 16 + wid * 4;
    const float2* f2 = (const float2*)f;
    float2 wv = ((const float2*)w)[lane];
    float2 v0 = f2[(size_t)(base + 0) * 64 + lane];
    float2 v1 = f2[(size_t)(base + 1) * 64 + lane];
    float2 v2 = f2[(size_t)(base + 2) * 64 + lane];
    float2 v3 = f2[(size_t)(base + 3) * 64 + lane];
    float p0 = fmaf(v0.x, wv.x, v0.y * wv.y);
    float p1 = fmaf(v1.x, wv.x, v1.y * wv.y);
    float p2 = fmaf(v2.x, wv.x, v2.y * wv.y);
    float p3 = fmaf(v3.x, wv.x, v3.y * wv.y);
    #pragma unroll
    for (int off = 32; off > 0; off >>= 1) {
        p0 += __shfl_xor(p0, off, 64);
        p1 += __shfl_xor(p1, off, 64);
        p2 += __shfl_xor(p2, off, 64);
        p3 += __shfl_xor(p3, off, 64);
    }
    float ws_sum = 0.f;
    if (lane < 4) {
        int atom = base + lane;
        float pk = p0;
        pk = (lane == 1) ? p1 : pk;
        pk = (lane == 2) ? p2 : pk;
        pk = (lane == 3) ? p3 : pk;
        pk += ztab[z[atom]];
        xqp[atom] = make_float4(xyz[3*atom], xyz[3*atom+1], xyz[3*atom+2], pk);
        ws_sum = pk;
    }
    ws_sum += __shfl_xor(ws_sum, 1, 64);
    ws_sum += __shfl_xor(ws_sum, 2, 64);

    __shared__ float lred[4];
    if (lane == 0) lred[wid] = ws_sum;
    __syncthreads();
    if (t == 0) qpart[b] = lred[0] + lred[1] + lred[2] + lred[3];
}

// ---------------- kernel B: pairwise energy ---------------------------------
// 1200 triangular blocks x 256 threads. Inner loop: 2 j-atoms/iter with
// independent chains + accumulators (forces ILP; launch_bounds(256,4) allows
// 128 VGPRs). Unconditional part: term = qq/r (exact for r >= 7.5).
// Switch correction qq*fs*(t1-t2) only under per-wave __any(r2 < 56.25).
__global__ __launch_bounds__(256, 4) void pair_kernel(
    const float4* __restrict__ xqp, const float* __restrict__ qpart,
    const float* __restrict__ total_charge,
    float* __restrict__ qout, float* __restrict__ epart,
    unsigned int* __restrict__ ctr1, unsigned int* __restrict__ ctr2,
    float* __restrict__ out0)
{
    int t = threadIdx.x, b = blockIdx.x;
    int lane = t & 63, wid = t >> 6;
    __shared__ float lred[4];
    __shared__ float4 sj[64];

    // charge correction from the 384 per-block partials
    float s = qpart[t];
    if (t < NPRED - 256) s += qpart[256 + t];
    #pragma unroll
    for (int off = 32; off > 0; off >>= 1)
        s += __shfl_xor(s, off, 64);
    if (lane == 0) lred[wid] = s;
    __syncthreads();
    float S = lred[0] + lred[1] + lred[2] + lred[3];
    float corr = (total_charge[0] - S) * (1.0f / (float)N_ATOMS);

    // decode triangular (bi, bj)
    int bi = 0, off = 0;
    while (b >= off + (96 - 4 * bi)) { off += 96 - 4 * bi; ++bi; }
    int bj = 4 * bi + (b - off);

    int gj0 = bj * 64;
    if (t < 64) {
        float4 a = xqp[gj0 + t];
        a.w += corr;
        sj[t] = a;
    }
    int gi = bi * 256 + t;
    float4 pi = xqp[gi];
    float qi = pi.w + corr;
    if (bj == 4 * bi) qout[gi] = qi;
    __syncthreads();

    int jthresh = gi - gj0;                   // pair valid iff jj > jthresh
    float acc0 = 0.f, acc1 = 0.f;
    #pragma unroll 2
    for (int jj = 0; jj < 64; jj += 2) {
        float4 pa = sj[jj];
        float4 pb = sj[jj + 1];
        float dxa = pi.x - pa.x, dya = pi.y - pa.y, dza = pi.z - pa.z;
        float dxb = pi.x - pb.x, dyb = pi.y - pb.y, dzb = pi.z - pb.z;
        float r2a = fmaf(dxa, dxa, fmaf(dya, dya, dza * dza));
        float r2b = fmaf(dxb, dxb, fmaf(dyb, dyb, dzb * dzb));
        bool ma = (jj     > jthresh) && (r2a > 0.f);
        bool mb = (jj + 1 > jthresh) && (r2b > 0.f);
        float r2sa = ma ? r2a : 1e8f;
        float r2sb = mb ? r2b : 1e8f;
        float qqa  = ma ? qi * pa.w : 0.f;
        float qqb  = mb ? qi * pb.w : 0.f;
        float t2a = __builtin_amdgcn_rsqf(r2sa);           // 1/r
        float t2b = __builtin_amdgcn_rsqf(r2sb);
        acc0 = fmaf(qqa, t2a, acc0);                       // exact for r>=7.5
        acc1 = fmaf(qqb, t2b, acc1);
        if (__any(fminf(r2sa, r2sb) < 56.25f)) {
            // switch correction: qq * fs * (t1 - t2); fs==0 for r>=7.5 lanes
            float ua = fmaf(r2sa * t2a, 0.2f, -0.5f);      // (r-2.5)/5
            float ub = fmaf(r2sb * t2b, 0.2f, -0.5f);
            ua = fminf(fmaxf(ua, 1e-3f), 0.999f);
            ub = fminf(fmaxf(ub, 1e-3f), 0.999f);
            float da = (ua + ua - 1.f) * __builtin_amdgcn_rcpf(fmaf(-ua, ua, ua));
            float db = (ub + ub - 1.f) * __builtin_amdgcn_rcpf(fmaf(-ub, ub, ub));
            float fa = __builtin_amdgcn_rcpf(1.f + __expf(da));
            float fb = __builtin_amdgcn_rcpf(1.f + __expf(db));
            float t1a = __builtin_amdgcn_rsqf(r2sa + 1.f);
            float t1b = __builtin_amdgcn_rsqf(r2sb + 1.f);
            acc0 = fmaf(qqa * fa, t1a - t2a, acc0);
            acc1 = fmaf(qqb * fb, t1b - t2b, acc1);
        }
    }
    float acc = acc0 + acc1;

    #pragma unroll
    for (int o2 = 32; o2 > 0; o2 >>= 1)
        acc += __shfl_down(acc, o2, 64);
    __syncthreads();                          // lred reuse
    if (lane == 0) lred[wid] = acc;
    __syncthreads();
    if (t == 0) {
        float be = lred[0] + lred[1] + lred[2] + lred[3];
        atomicAdd(&epart[(b & 63) * PAD], be);
    }

    // two-level completion + finalize (wave 0 only)
    if (t < 64) {
        bool last = false;
        if (t == 0) {
            int g = b & 63;
            unsigned int gcnt = (g < 48) ? 19u : 18u;   // 48*19 + 16*18 = 1200
            __threadfence();
            unsigned int o1 = atomicAdd(&ctr1[g * PAD], 1u);
            if (o1 == gcnt - 1u) {
                __threadfence();
                unsigned int o2c = atomicAdd(ctr2, 1u);
                last = (o2c == 63u);
            }
        }
        last = (bool)__shfl((int)last, 0, 64);
        if (last) {
            float e = atomicAdd(&epart[t * PAD], 0.0f);   // coherent read
            #pragma unroll
            for (int o2 = 32; o2 > 0; o2 >>= 1)
                e += __shfl_down(e, o2, 64);
            if (t == 0) out0[0] = KE_KCAL * e;
        }
    }
}

extern "C" void kernel_launch(void* const* d_in, const int* in_sizes, int n_in,
                              void* d_out, int out_size, void* d_ws, size_t ws_size,
                              hipStream_t stream) {
    const float* f    = (const float*)d_in[0];
    const int*   z    = (const int*)  d_in[1];
    const float* xyz  = (const float*)d_in[2];
    const float* qtot = (const float*)d_in[3];
    const float* w    = (const float*)d_in[4];
    const float* ztab = (const float*)d_in[5];
    float* out = (float*)d_out;            // out[0]=energy, out[1..N]=q

    // ws: [0, 8192) epart padded | [8192, 16384) ctr1 padded | [16384] ctr2
    //     [16896, +1536) qpart[384] | [32768, +98304) xqp[N] float4
    char* wsb = (char*)d_ws;
    float*        epart = (float*)(wsb + 0);
    unsigned int* ctr1  = (unsigned int*)(wsb + 8192);
    unsigned int* ctr2  = (unsigned int*)(wsb + 16384);
    float*        qpart = (float*)(wsb + 16896);
    float4*       xqp   = (float4*)(wsb + 32768);

    pred_kernel<<<NPRED, 256, 0, stream>>>(f, z, w, ztab, xyz,
                                           qpart, xqp, epart, ctr1, ctr2);
    pair_kernel<<<NREAL, 256, 0, stream>>>(xqp, qpart, qtot, out + 1, epart,
                                           ctr1, ctr2, out);
}